// Round 1
// baseline (468.935 us; speedup 1.0000x reference)
//
#include <hip/hip_runtime.h>

#define Bv 2
#define Wv 1024
#define Dv 1024
#define Rv 16

static __device__ __forceinline__ float sigmoidf_(float x) {
    return 1.0f / (1.0f + expf(-x));
}

// ---------------- RMSNorm: one block per row, 256 threads, D=1024 ----------------
__global__ void rmsnorm_kernel(const float* __restrict__ x,
                               const float* __restrict__ scale,
                               float* __restrict__ out) {
    int row = blockIdx.x;
    int t = threadIdx.x;
    const float* xr = x + (size_t)row * Dv;
    float4 v = *(const float4*)(xr + t * 4);
    float ss = v.x * v.x + v.y * v.y + v.z * v.z + v.w * v.w;
    for (int off = 32; off > 0; off >>= 1) ss += __shfl_down(ss, off);
    __shared__ float wsum[4];
    __shared__ float inv_s;
    int lane = t & 63, wid = t >> 6;
    if (lane == 0) wsum[wid] = ss;
    __syncthreads();
    if (t == 0) {
        float tot = wsum[0] + wsum[1] + wsum[2] + wsum[3];
        inv_s = rsqrtf(tot * (1.0f / Dv) + 1e-8f);
    }
    __syncthreads();
    float inv = inv_s;
    float4 sc = *(const float4*)(scale + t * 4);
    float4 o;
    o.x = v.x * inv * sc.x;
    o.y = v.y * inv * sc.y;
    o.z = v.z * inv * sc.z;
    o.w = v.w * inv * sc.w;
    *(float4*)(out + (size_t)row * Dv + t * 4) = o;
}

// ---------------- q,k: per row, h_norm @ u / @ v then l2norm ----------------
__global__ void qk_kernel(const float* __restrict__ hn,
                          const float* __restrict__ u,
                          const float* __restrict__ v,
                          float* __restrict__ qo, float* __restrict__ ko) {
    int row = blockIdx.x;
    int t = threadIdx.x;  // 256
    const float* hr = hn + (size_t)row * Dv;
    float accq[Rv], acck[Rv];
#pragma unroll
    for (int r = 0; r < Rv; r++) { accq[r] = 0.f; acck[r] = 0.f; }
    float4 hv = *(const float4*)(hr + t * 4);
    float hvv[4] = {hv.x, hv.y, hv.z, hv.w};
#pragma unroll
    for (int j = 0; j < 4; j++) {
        int d = t * 4 + j;
        const float4* ur = (const float4*)(u + (size_t)d * Rv);
        const float4* vr = (const float4*)(v + (size_t)d * Rv);
#pragma unroll
        for (int c = 0; c < 4; c++) {
            float4 uu = ur[c], vv = vr[c];
            accq[c * 4 + 0] += hvv[j] * uu.x;
            accq[c * 4 + 1] += hvv[j] * uu.y;
            accq[c * 4 + 2] += hvv[j] * uu.z;
            accq[c * 4 + 3] += hvv[j] * uu.w;
            acck[c * 4 + 0] += hvv[j] * vv.x;
            acck[c * 4 + 1] += hvv[j] * vv.y;
            acck[c * 4 + 2] += hvv[j] * vv.z;
            acck[c * 4 + 3] += hvv[j] * vv.w;
        }
    }
#pragma unroll
    for (int r = 0; r < Rv; r++) {
        for (int off = 32; off > 0; off >>= 1) {
            accq[r] += __shfl_down(accq[r], off);
            acck[r] += __shfl_down(acck[r], off);
        }
    }
    __shared__ float red[4][2 * Rv];
    __shared__ float fin[2 * Rv];
    int lane = t & 63, wid = t >> 6;
    if (lane == 0) {
#pragma unroll
        for (int r = 0; r < Rv; r++) {
            red[wid][r] = accq[r];
            red[wid][Rv + r] = acck[r];
        }
    }
    __syncthreads();
    if (t < 2 * Rv) fin[t] = red[0][t] + red[1][t] + red[2][t] + red[3][t];
    __syncthreads();
    if (t < Rv) {
        float ss = 0.f;
#pragma unroll
        for (int r = 0; r < Rv; r++) { float x = fin[r]; ss += x * x; }
        float nrm = fmaxf(sqrtf(ss), 1e-8f);
        qo[(size_t)row * Rv + t] = fin[t] / nrm;
    } else if (t < 2 * Rv) {
        float ss = 0.f;
#pragma unroll
        for (int r = Rv; r < 2 * Rv; r++) { float x = fin[r]; ss += x * x; }
        float nrm = fmaxf(sqrtf(ss), 1e-8f);
        ko[(size_t)row * Rv + (t - Rv)] = fin[t] / nrm;
    }
}

// ---------------- gamma^delta table: gpow[delta*16 + r] ----------------
__global__ void gpow_kernel(const float* __restrict__ decay_logit,
                            float* __restrict__ gpow) {
    int idx = blockIdx.x * 256 + threadIdx.x;
    if (idx >= Wv * Rv) return;
    int r = idx & (Rv - 1);
    int delta = idx >> 4;
    float gamma = 0.85f + 0.15f * sigmoidf_(decay_logit[r]);
    gpow[idx] = expf((float)delta * logf(gamma));
}

// ---------------- S[b,i,j] = gate*kb[i,j] + alpha*sum_r q*k*gamma^(i-j), causal ----------------
__global__ void sbuild_kernel(const float* __restrict__ qm, const float* __restrict__ km,
                              const float* __restrict__ kbase,
                              const float* __restrict__ gate_logit,
                              const float* __restrict__ alpha_logit,
                              const float* __restrict__ gpow,
                              float* __restrict__ S) {
    int b = blockIdx.z;
    int i = blockIdx.y * 16 + threadIdx.y;
    int j = blockIdx.x * 16 + threadIdx.x;
    float* Sp = S + ((size_t)b * Wv + i) * Wv + j;
    if (j > i) { *Sp = 0.f; return; }
    float gate = sigmoidf_(gate_logit[0]);
    float alpha = sigmoidf_(alpha_logit[0]);
    const float4* qr = (const float4*)(qm + ((size_t)b * Wv + i) * Rv);
    const float4* kr = (const float4*)(km + ((size_t)b * Wv + j) * Rv);
    const float4* gp = (const float4*)(gpow + (size_t)(i - j) * Rv);
    float s = 0.f;
#pragma unroll
    for (int c = 0; c < 4; c++) {
        float4 qq = qr[c], kk = kr[c], gg = gp[c];
        s += qq.x * kk.x * gg.x + qq.y * kk.y * gg.y + qq.z * kk.z * gg.z + qq.w * kk.w * gg.w;
    }
    *Sp = gate * kbase[(size_t)i * Wv + j] + alpha * s;
}

// ---------------- generic f32 GEMM: C = [gelu](A@B + bias) + C0, optional batch ----------------
// 64x64 tile, 256 threads, 4x4 per thread, K-tile 16.
template <bool GELU>
__global__ void gemm_kernel(const float* __restrict__ A, const float* __restrict__ Bm,
                            const float* __restrict__ C0, const float* __restrict__ bias,
                            float* __restrict__ C,
                            int M, int N, int K,
                            long sA, long sB, long sC0, long sC) {
    __shared__ float As[16][64];
    __shared__ float Bs[16][64];
    int bz = blockIdx.z;
    A += (size_t)bz * sA;
    Bm += (size_t)bz * sB;
    C += (size_t)bz * sC;
    const float* C0p = C0 ? (C0 + (size_t)bz * sC0) : nullptr;
    int m0 = blockIdx.y * 64, n0 = blockIdx.x * 64;
    int t = threadIdx.x;
    int tx = t & 15, ty = t >> 4;
    float acc[4][4] = {};
    for (int k0 = 0; k0 < K; k0 += 16) {
        {
            int row = t >> 2, cg = (t & 3) * 4;
            float4 a = *(const float4*)(A + (size_t)(m0 + row) * K + k0 + cg);
            As[cg + 0][row] = a.x;
            As[cg + 1][row] = a.y;
            As[cg + 2][row] = a.z;
            As[cg + 3][row] = a.w;
        }
        {
            int kk = t >> 4, ncg = (t & 15) * 4;
            float4 b = *(const float4*)(Bm + (size_t)(k0 + kk) * N + n0 + ncg);
            *(float4*)&Bs[kk][ncg] = b;
        }
        __syncthreads();
#pragma unroll
        for (int kk = 0; kk < 16; kk++) {
            float4 a = *(const float4*)&As[kk][ty * 4];
            float4 bb = *(const float4*)&Bs[kk][tx * 4];
            float av[4] = {a.x, a.y, a.z, a.w};
            float bv[4] = {bb.x, bb.y, bb.z, bb.w};
#pragma unroll
            for (int i = 0; i < 4; i++)
#pragma unroll
                for (int j = 0; j < 4; j++) acc[i][j] += av[i] * bv[j];
        }
        __syncthreads();
    }
#pragma unroll
    for (int i = 0; i < 4; i++) {
        int m = m0 + ty * 4 + i;
        int n = n0 + tx * 4;
        float r[4] = {acc[i][0], acc[i][1], acc[i][2], acc[i][3]};
        if (bias) {
            float4 bb = *(const float4*)(bias + n);
            r[0] += bb.x; r[1] += bb.y; r[2] += bb.z; r[3] += bb.w;
        }
        if (GELU) {
#pragma unroll
            for (int j = 0; j < 4; j++)
                r[j] = 0.5f * r[j] * (1.0f + erff(r[j] * 0.7071067811865476f));
        }
        if (C0p) {
            float4 cc = *(const float4*)(C0p + (size_t)m * N + n);
            r[0] += cc.x; r[1] += cc.y; r[2] += cc.z; r[3] += cc.w;
        }
        float4 o = {r[0], r[1], r[2], r[3]};
        *(float4*)(C + (size_t)m * N + n) = o;
    }
}

extern "C" void kernel_launch(void* const* d_in, const int* in_sizes, int n_in,
                              void* d_out, int out_size, void* d_ws, size_t ws_size,
                              hipStream_t stream) {
    const float* h = (const float*)d_in[0];
    const float* decay_logit = (const float*)d_in[1];
    const float* k_base = (const float*)d_in[2];
    const float* gate_logit = (const float*)d_in[3];
    const float* u = (const float*)d_in[4];
    const float* v = (const float*)d_in[5];
    const float* alpha_logit = (const float*)d_in[6];
    const float* proj_w = (const float*)d_in[7];
    const float* proj_b = (const float*)d_in[8];
    const float* n1 = (const float*)d_in[9];
    const float* n2 = (const float*)d_in[10];
    const float* up_w = (const float*)d_in[11];
    const float* up_b = (const float*)d_in[12];
    const float* down_w = (const float*)d_in[13];
    const float* down_b = (const float*)d_in[14];
    float* out = (float*)d_out;

    char* ws = (char*)d_ws;
    float* h_norm = (float*)ws;            ws += (size_t)Bv * Wv * Dv * 4;      // 8 MB
    float* qm = (float*)ws;                ws += (size_t)Bv * Wv * Rv * 4;      // 128 KB
    float* km = (float*)ws;                ws += (size_t)Bv * Wv * Rv * 4;      // 128 KB
    float* gpow = (float*)ws;              ws += (size_t)Wv * Rv * 4;           // 64 KB
    float* S = (float*)ws;                 ws += (size_t)Bv * Wv * Wv * 4;      // 8 MB
    float* out_s = (float*)ws;             ws += (size_t)Bv * Wv * Dv * 4;      // 8 MB
    float* h2 = (float*)ws;                ws += (size_t)Bv * Wv * Dv * 4;      // 8 MB
    float* h2n = (float*)ws;               ws += (size_t)Bv * Wv * Dv * 4;      // 8 MB
    float* g = (float*)ws;                 ws += (size_t)Bv * Wv * 2 * Dv * 4;  // 16 MB

    int rows = Bv * Wv;  // 2048

    // 1. h_norm = rmsnorm(h, norm1_scale)
    rmsnorm_kernel<<<rows, 256, 0, stream>>>(h, n1, h_norm);
    // 2. q,k
    qk_kernel<<<rows, 256, 0, stream>>>(h_norm, u, v, qm, km);
    // 3. gamma^delta table
    gpow_kernel<<<(Wv * Rv + 255) / 256, 256, 0, stream>>>(decay_logit, gpow);
    // 4. S matrix
    sbuild_kernel<<<dim3(Wv / 16, Wv / 16, Bv), dim3(16, 16), 0, stream>>>(
        qm, km, k_base, gate_logit, alpha_logit, gpow, S);
    // 5. out_s = S @ h_norm   (batched)
    gemm_kernel<false><<<dim3(Dv / 64, Wv / 64, Bv), 256, 0, stream>>>(
        S, h_norm, nullptr, nullptr, out_s, Wv, Dv, Wv,
        (long)Wv * Wv, (long)Wv * Dv, 0, (long)Wv * Dv);
    // 6. h2 = h + out_s @ proj_w + proj_b
    gemm_kernel<false><<<dim3(Dv / 64, rows / 64, 1), 256, 0, stream>>>(
        out_s, proj_w, h, proj_b, h2, rows, Dv, Dv, 0, 0, 0, 0);
    // 7. h2n = rmsnorm(h2, norm2_scale)
    rmsnorm_kernel<<<rows, 256, 0, stream>>>(h2, n2, h2n);
    // 8. g = gelu(h2n @ up_w + up_b)
    gemm_kernel<true><<<dim3(2 * Dv / 64, rows / 64, 1), 256, 0, stream>>>(
        h2n, up_w, nullptr, up_b, g, rows, 2 * Dv, Dv, 0, 0, 0, 0);
    // 9. out = h2 + g @ down_w + down_b
    gemm_kernel<false><<<dim3(Dv / 64, rows / 64, 1), 256, 0, stream>>>(
        g, down_w, h2, down_b, out, rows, Dv, 2 * Dv, 0, 0, 0, 0);
}

// Round 2
// 193.650 us; speedup vs baseline: 2.4216x; 2.4216x over previous
//
#include <hip/hip_runtime.h>

#define Bv 2
#define Wv 1024
#define Dv 1024
#define Rv 16

typedef __bf16 bf16;
typedef __attribute__((ext_vector_type(8))) __bf16 bf16x8;
typedef __attribute__((ext_vector_type(4))) __bf16 bf16x4;
typedef __attribute__((ext_vector_type(4))) float f32x4;

static __device__ __forceinline__ float sigmoidf_(float x) {
    return 1.0f / (1.0f + expf(-x));
}

static __device__ __forceinline__ void gload_lds16(const void* g, void* l) {
    __builtin_amdgcn_global_load_lds(
        (const __attribute__((address_space(1))) unsigned int*)g,
        (__attribute__((address_space(3))) unsigned int*)l, 16, 0, 0);
}

// ---------------- RMSNorm: one block per row, 256 threads, D=1024 ----------------
// OUTBF16: write bf16 row-major (feeds next GEMM's A operand) instead of f32.
template <bool OUTBF16>
__global__ void rmsnorm_kernel(const float* __restrict__ x,
                               const float* __restrict__ scale,
                               void* __restrict__ out) {
    int row = blockIdx.x;
    int t = threadIdx.x;
    const float* xr = x + (size_t)row * Dv;
    float4 v = *(const float4*)(xr + t * 4);
    float ss = v.x * v.x + v.y * v.y + v.z * v.z + v.w * v.w;
    for (int off = 32; off > 0; off >>= 1) ss += __shfl_down(ss, off);
    __shared__ float wsum[4];
    __shared__ float inv_s;
    int lane = t & 63, wid = t >> 6;
    if (lane == 0) wsum[wid] = ss;
    __syncthreads();
    if (t == 0) {
        float tot = wsum[0] + wsum[1] + wsum[2] + wsum[3];
        inv_s = rsqrtf(tot * (1.0f / Dv) + 1e-8f);
    }
    __syncthreads();
    float inv = inv_s;
    float4 sc = *(const float4*)(scale + t * 4);
    float o0 = v.x * inv * sc.x;
    float o1 = v.y * inv * sc.y;
    float o2 = v.z * inv * sc.z;
    float o3 = v.w * inv * sc.w;
    if (OUTBF16) {
        bf16x4 ob = {(bf16)o0, (bf16)o1, (bf16)o2, (bf16)o3};
        *(bf16x4*)((bf16*)out + (size_t)row * Dv + t * 4) = ob;
    } else {
        float4 o = {o0, o1, o2, o3};
        *(float4*)((float*)out + (size_t)row * Dv + t * 4) = o;
    }
}

// ---------------- q,k: per row, h_norm @ u / @ v then l2norm ----------------
__global__ void qk_kernel(const float* __restrict__ hn,
                          const float* __restrict__ u,
                          const float* __restrict__ v,
                          float* __restrict__ qo, float* __restrict__ ko) {
    int row = blockIdx.x;
    int t = threadIdx.x;  // 256
    const float* hr = hn + (size_t)row * Dv;
    float accq[Rv], acck[Rv];
#pragma unroll
    for (int r = 0; r < Rv; r++) { accq[r] = 0.f; acck[r] = 0.f; }
    float4 hv = *(const float4*)(hr + t * 4);
    float hvv[4] = {hv.x, hv.y, hv.z, hv.w};
#pragma unroll
    for (int j = 0; j < 4; j++) {
        int d = t * 4 + j;
        const float4* ur = (const float4*)(u + (size_t)d * Rv);
        const float4* vr = (const float4*)(v + (size_t)d * Rv);
#pragma unroll
        for (int c = 0; c < 4; c++) {
            float4 uu = ur[c], vv = vr[c];
            accq[c * 4 + 0] += hvv[j] * uu.x;
            accq[c * 4 + 1] += hvv[j] * uu.y;
            accq[c * 4 + 2] += hvv[j] * uu.z;
            accq[c * 4 + 3] += hvv[j] * uu.w;
            acck[c * 4 + 0] += hvv[j] * vv.x;
            acck[c * 4 + 1] += hvv[j] * vv.y;
            acck[c * 4 + 2] += hvv[j] * vv.z;
            acck[c * 4 + 3] += hvv[j] * vv.w;
        }
    }
#pragma unroll
    for (int r = 0; r < Rv; r++) {
        for (int off = 32; off > 0; off >>= 1) {
            accq[r] += __shfl_down(accq[r], off);
            acck[r] += __shfl_down(acck[r], off);
        }
    }
    __shared__ float red[4][2 * Rv];
    __shared__ float fin[2 * Rv];
    int lane = t & 63, wid = t >> 6;
    if (lane == 0) {
#pragma unroll
        for (int r = 0; r < Rv; r++) {
            red[wid][r] = accq[r];
            red[wid][Rv + r] = acck[r];
        }
    }
    __syncthreads();
    if (t < 2 * Rv) fin[t] = red[0][t] + red[1][t] + red[2][t] + red[3][t];
    __syncthreads();
    if (t < Rv) {
        float ss = 0.f;
#pragma unroll
        for (int r = 0; r < Rv; r++) { float x = fin[r]; ss += x * x; }
        float nrm = fmaxf(sqrtf(ss), 1e-8f);
        qo[(size_t)row * Rv + t] = fin[t] / nrm;
    } else if (t < 2 * Rv) {
        float ss = 0.f;
#pragma unroll
        for (int r = Rv; r < 2 * Rv; r++) { float x = fin[r]; ss += x * x; }
        float nrm = fmaxf(sqrtf(ss), 1e-8f);
        ko[(size_t)row * Rv + (t - Rv)] = fin[t] / nrm;
    }
}

// ---------------- gamma^delta table: gpow[delta*16 + r] ----------------
__global__ void gpow_kernel(const float* __restrict__ decay_logit,
                            float* __restrict__ gpow) {
    int idx = blockIdx.x * 256 + threadIdx.x;
    if (idx >= Wv * Rv) return;
    int r = idx & (Rv - 1);
    int delta = idx >> 4;
    float gamma = 0.85f + 0.15f * sigmoidf_(decay_logit[r]);
    gpow[idx] = expf((float)delta * logf(gamma));
}

// ---------------- S[b,i,j] = gate*kb[i,j] + alpha*sum_r q*k*gamma^(i-j), causal; bf16 out ----
__global__ void sbuild_kernel(const float* __restrict__ qm, const float* __restrict__ km,
                              const float* __restrict__ kbase,
                              const float* __restrict__ gate_logit,
                              const float* __restrict__ alpha_logit,
                              const float* __restrict__ gpow,
                              bf16* __restrict__ S) {
    int b = blockIdx.z;
    int i = blockIdx.y * 16 + threadIdx.y;
    int j = blockIdx.x * 16 + threadIdx.x;
    bf16* Sp = S + ((size_t)b * Wv + i) * Wv + j;
    if (j > i) { *Sp = (bf16)0.f; return; }
    float gate = sigmoidf_(gate_logit[0]);
    float alpha = sigmoidf_(alpha_logit[0]);
    const float4* qr = (const float4*)(qm + ((size_t)b * Wv + i) * Rv);
    const float4* kr = (const float4*)(km + ((size_t)b * Wv + j) * Rv);
    const float4* gp = (const float4*)(gpow + (size_t)(i - j) * Rv);
    float s = 0.f;
#pragma unroll
    for (int c = 0; c < 4; c++) {
        float4 qq = qr[c], kk = kr[c], gg = gp[c];
        s += qq.x * kk.x * gg.x + qq.y * kk.y * gg.y + qq.z * kk.z * gg.z + qq.w * kk.w * gg.w;
    }
    *Sp = (bf16)(gate * kbase[(size_t)i * Wv + j] + alpha * s);
}

// ---------------- transpose-cast f32 [rows][cols] -> bf16 [cols][rows] ----------------
__global__ void tcast_kernel(const float* __restrict__ in, bf16* __restrict__ out,
                             int rows, int cols, long sIn, long sOut) {
    __shared__ float tile[32][33];
    int bz = blockIdx.z;
    in += (size_t)bz * sIn;
    out += (size_t)bz * sOut;
    int r0 = blockIdx.y * 32, c0 = blockIdx.x * 32;
    int t = threadIdx.x;  // 256
    int r = t >> 3, c4 = (t & 7) * 4;
    float4 v = *(const float4*)(in + (size_t)(r0 + r) * cols + c0 + c4);
    tile[r][c4 + 0] = v.x;
    tile[r][c4 + 1] = v.y;
    tile[r][c4 + 2] = v.z;
    tile[r][c4 + 3] = v.w;
    __syncthreads();
    int n = t >> 3, k4 = (t & 7) * 4;
    bf16x4 ob = {(bf16)tile[k4 + 0][n], (bf16)tile[k4 + 1][n],
                 (bf16)tile[k4 + 2][n], (bf16)tile[k4 + 3][n]};
    *(bf16x4*)(out + (size_t)(c0 + n) * rows + r0 + k4) = ob;
}

// ---------------- MFMA GEMM: C = [gelu](A @ Bt^T + bias) [+ res], A:[M][K] Bt:[N][K] bf16 ----
// BM=128, BK=32, 256 threads = 4 waves in 2x2; wave computes 64 x (BN/2).
template <int BN, bool GELU, bool OUT_BF16, bool HAS_RES, bool CAUSAL>
__global__ __launch_bounds__(256, 2) void mfma_gemm(
    const bf16* __restrict__ A, const bf16* __restrict__ Bt,
    const float* __restrict__ bias, const float* __restrict__ res,
    void* __restrict__ Cout, int M, int N, int K,
    long sA, long sB, long sC) {
    constexpr int BM = 128;
    constexpr int BK = 32;
    constexpr int MI = 4;
    constexpr int NI = BN / 32;
    __shared__ bf16 As[BM * BK];
    __shared__ bf16 Bs[BN * BK];
    int bz = blockIdx.z;
    A += (size_t)bz * sA;
    Bt += (size_t)bz * sB;
    const int m0 = blockIdx.y * BM, n0 = blockIdx.x * BN;
    const int t = threadIdx.x;
    const int lane = t & 63, wid = t >> 6;
    const int wm = wid >> 1, wn = wid & 1;
    f32x4 acc[MI][NI] = {};

    const int Klim = CAUSAL ? (m0 + BM < K ? m0 + BM : K) : K;

    for (int k0 = 0; k0 < Klim; k0 += BK) {
        __syncthreads();  // all waves done reading LDS from previous step
#pragma unroll
        for (int it = 0; it < 2; ++it) {  // A tile: 128x32 bf16 = 8KB
            int flat = it * 256 + t;
            int r = flat >> 2, c = flat & 3;
            gload_lds16(A + (size_t)(m0 + r) * K + k0 + c * 8,
                        As + it * 2048 + wid * 512);
        }
#pragma unroll
        for (int it = 0; it < BN / 64; ++it) {  // B tile: BNx32 bf16
            int flat = it * 256 + t;
            int r = flat >> 2, c = flat & 3;
            gload_lds16(Bt + (size_t)(n0 + r) * K + k0 + c * 8,
                        Bs + it * 2048 + wid * 512);
        }
        __syncthreads();  // compiler drains vmcnt before s_barrier

        bf16x8 af[MI], bfr[NI];
#pragma unroll
        for (int mi = 0; mi < MI; ++mi)
            af[mi] = *(const bf16x8*)&As[(wm * 64 + mi * 16 + (lane & 15)) * BK + (lane >> 4) * 8];
#pragma unroll
        for (int ni = 0; ni < NI; ++ni)
            bfr[ni] = *(const bf16x8*)&Bs[(wn * (BN / 2) + ni * 16 + (lane & 15)) * BK + (lane >> 4) * 8];
#pragma unroll
        for (int mi = 0; mi < MI; ++mi)
#pragma unroll
            for (int ni = 0; ni < NI; ++ni)
                acc[mi][ni] = __builtin_amdgcn_mfma_f32_16x16x32_bf16(af[mi], bfr[ni], acc[mi][ni], 0, 0, 0);
    }

    const int row_base = m0 + wm * 64;
    const int col_base = n0 + wn * (BN / 2);
    const float* resp = HAS_RES ? res + (size_t)bz * sC : nullptr;
#pragma unroll
    for (int mi = 0; mi < MI; ++mi) {
#pragma unroll
        for (int ni = 0; ni < NI; ++ni) {
            int col = col_base + ni * 16 + (lane & 15);
            float bv = bias ? bias[col] : 0.f;
#pragma unroll
            for (int r = 0; r < 4; ++r) {
                int row = row_base + mi * 16 + (lane >> 4) * 4 + r;
                float val = acc[mi][ni][r] + bv;
                if (GELU) val = 0.5f * val * (1.0f + erff(val * 0.7071067811865476f));
                if (HAS_RES) val += resp[(size_t)row * N + col];
                if (OUT_BF16)
                    ((bf16*)Cout)[(size_t)bz * sC + (size_t)row * N + col] = (bf16)val;
                else
                    ((float*)Cout)[(size_t)bz * sC + (size_t)row * N + col] = val;
            }
        }
    }
}

extern "C" void kernel_launch(void* const* d_in, const int* in_sizes, int n_in,
                              void* d_out, int out_size, void* d_ws, size_t ws_size,
                              hipStream_t stream) {
    const float* h = (const float*)d_in[0];
    const float* decay_logit = (const float*)d_in[1];
    const float* k_base = (const float*)d_in[2];
    const float* gate_logit = (const float*)d_in[3];
    const float* u = (const float*)d_in[4];
    const float* v = (const float*)d_in[5];
    const float* alpha_logit = (const float*)d_in[6];
    const float* proj_w = (const float*)d_in[7];
    const float* proj_b = (const float*)d_in[8];
    const float* n1 = (const float*)d_in[9];
    const float* n2 = (const float*)d_in[10];
    const float* up_w = (const float*)d_in[11];
    const float* up_b = (const float*)d_in[12];
    const float* down_w = (const float*)d_in[13];
    const float* down_b = (const float*)d_in[14];
    float* out = (float*)d_out;

    char* ws = (char*)d_ws;
    float* h_norm = (float*)ws;   ws += (size_t)Bv * Wv * Dv * 4;       // 8 MB f32
    bf16* h_normT = (bf16*)ws;    ws += (size_t)Bv * Dv * Wv * 2;       // 4 MB bf16 [b][D][W]
    float* qm = (float*)ws;       ws += (size_t)Bv * Wv * Rv * 4;
    float* km = (float*)ws;       ws += (size_t)Bv * Wv * Rv * 4;
    float* gpow = (float*)ws;     ws += (size_t)Wv * Rv * 4;
    bf16* S = (bf16*)ws;          ws += (size_t)Bv * Wv * Wv * 2;       // 4 MB
    bf16* out_s = (bf16*)ws;      ws += (size_t)Bv * Wv * Dv * 2;       // 4 MB
    float* h2 = (float*)ws;       ws += (size_t)Bv * Wv * Dv * 4;       // 8 MB
    bf16* h2n = (bf16*)ws;        ws += (size_t)Bv * Wv * Dv * 2;       // 4 MB
    bf16* g = (bf16*)ws;          ws += (size_t)Bv * Wv * 2 * Dv * 2;   // 8 MB
    bf16* proj_wT = (bf16*)ws;    ws += (size_t)Dv * Dv * 2;            // 2 MB
    bf16* up_wT = (bf16*)ws;      ws += (size_t)2 * Dv * Dv * 2;        // 4 MB
    bf16* down_wT = (bf16*)ws;    ws += (size_t)2 * Dv * Dv * 2;        // 4 MB

    int rows = Bv * Wv;  // 2048

    // 1. h_norm = rmsnorm(h, norm1_scale)  (f32, feeds qk + transpose)
    rmsnorm_kernel<false><<<rows, 256, 0, stream>>>(h, n1, h_norm);
    // 2. weight transposes (bf16 [N][K]) + h_norm^T per batch
    tcast_kernel<<<dim3(32, 32, 1), 256, 0, stream>>>(proj_w, proj_wT, Dv, Dv, 0, 0);
    tcast_kernel<<<dim3(64, 32, 1), 256, 0, stream>>>(up_w, up_wT, Dv, 2 * Dv, 0, 0);
    tcast_kernel<<<dim3(32, 64, 1), 256, 0, stream>>>(down_w, down_wT, 2 * Dv, Dv, 0, 0);
    tcast_kernel<<<dim3(32, 32, Bv), 256, 0, stream>>>(h_norm, h_normT, Wv, Dv,
                                                       (long)Wv * Dv, (long)Dv * Wv);
    // 3. q,k
    qk_kernel<<<rows, 256, 0, stream>>>(h_norm, u, v, qm, km);
    // 4. gamma^delta table
    gpow_kernel<<<(Wv * Rv + 255) / 256, 256, 0, stream>>>(decay_logit, gpow);
    // 5. S matrix (bf16)
    sbuild_kernel<<<dim3(Wv / 16, Wv / 16, Bv), dim3(16, 16), 0, stream>>>(
        qm, km, k_base, gate_logit, alpha_logit, gpow, S);
    // 6. out_s = S @ h_norm  (batched, causal-K, bf16 out)
    mfma_gemm<64, false, true, false, true><<<dim3(Dv / 64, Wv / 128, Bv), 256, 0, stream>>>(
        S, h_normT, nullptr, nullptr, out_s, Wv, Dv, Wv,
        (long)Wv * Wv, (long)Dv * Wv, (long)Wv * Dv);
    // 7. h2 = h + out_s @ proj_w + proj_b  (f32 out)
    mfma_gemm<64, false, false, true, false><<<dim3(Dv / 64, rows / 128, 1), 256, 0, stream>>>(
        out_s, proj_wT, proj_b, h, h2, rows, Dv, Dv, 0, 0, 0);
    // 8. h2n = rmsnorm(h2, norm2_scale)  (bf16 out)
    rmsnorm_kernel<true><<<rows, 256, 0, stream>>>(h2, n2, h2n);
    // 9. g = gelu(h2n @ up_w + up_b)  (bf16 out)
    mfma_gemm<128, true, true, false, false><<<dim3(2 * Dv / 128, rows / 128, 1), 256, 0, stream>>>(
        h2n, up_wT, up_b, nullptr, g, rows, 2 * Dv, Dv, 0, 0, 0);
    // 10. out = h2 + g @ down_w + down_b  (f32 out)
    mfma_gemm<64, false, false, true, false><<<dim3(Dv / 64, rows / 128, 1), 256, 0, stream>>>(
        g, down_wT, down_b, h2, out, rows, Dv, 2 * Dv, 0, 0, 0);
}

// Round 3
// 155.793 us; speedup vs baseline: 3.0100x; 1.2430x over previous
//
#include <hip/hip_runtime.h>

#define Bv 2
#define Wv 1024
#define Dv 1024
#define Rv 16

typedef __bf16 bf16;
typedef __attribute__((ext_vector_type(8))) __bf16 bf16x8;
typedef __attribute__((ext_vector_type(4))) __bf16 bf16x4;
typedef __attribute__((ext_vector_type(4))) float f32x4;

static __device__ __forceinline__ float sigmoidf_(float x) {
    return 1.0f / (1.0f + expf(-x));
}

static __device__ __forceinline__ void gload_lds16(const void* g, void* l) {
    __builtin_amdgcn_global_load_lds(
        (const __attribute__((address_space(1))) unsigned int*)g,
        (__attribute__((address_space(3))) unsigned int*)l, 16, 0, 0);
}

// ---------------- RMSNorm: one block per row, 256 threads, D=1024 ----------------
template <bool OUTBF16>
__global__ void rmsnorm_kernel(const float* __restrict__ x,
                               const float* __restrict__ scale,
                               void* __restrict__ out) {
    int row = blockIdx.x;
    int t = threadIdx.x;
    const float* xr = x + (size_t)row * Dv;
    float4 v = *(const float4*)(xr + t * 4);
    float ss = v.x * v.x + v.y * v.y + v.z * v.z + v.w * v.w;
    for (int off = 32; off > 0; off >>= 1) ss += __shfl_down(ss, off);
    __shared__ float wsum[4];
    __shared__ float inv_s;
    int lane = t & 63, wid = t >> 6;
    if (lane == 0) wsum[wid] = ss;
    __syncthreads();
    if (t == 0) {
        float tot = wsum[0] + wsum[1] + wsum[2] + wsum[3];
        inv_s = rsqrtf(tot * (1.0f / Dv) + 1e-8f);
    }
    __syncthreads();
    float inv = inv_s;
    float4 sc = *(const float4*)(scale + t * 4);
    float o0 = v.x * inv * sc.x;
    float o1 = v.y * inv * sc.y;
    float o2 = v.z * inv * sc.z;
    float o3 = v.w * inv * sc.w;
    if (OUTBF16) {
        bf16x4 ob = {(bf16)o0, (bf16)o1, (bf16)o2, (bf16)o3};
        *(bf16x4*)((bf16*)out + (size_t)row * Dv + t * 4) = ob;
    } else {
        float4 o = {o0, o1, o2, o3};
        *(float4*)((float*)out + (size_t)row * Dv + t * 4) = o;
    }
}

// ---------------- q,k: per row, h_norm @ u / @ v then l2norm ----------------
__global__ void qk_kernel(const float* __restrict__ hn,
                          const float* __restrict__ u,
                          const float* __restrict__ v,
                          float* __restrict__ qo, float* __restrict__ ko) {
    int row = blockIdx.x;
    int t = threadIdx.x;  // 256
    const float* hr = hn + (size_t)row * Dv;
    float accq[Rv], acck[Rv];
#pragma unroll
    for (int r = 0; r < Rv; r++) { accq[r] = 0.f; acck[r] = 0.f; }
    float4 hv = *(const float4*)(hr + t * 4);
    float hvv[4] = {hv.x, hv.y, hv.z, hv.w};
#pragma unroll
    for (int j = 0; j < 4; j++) {
        int d = t * 4 + j;
        const float4* ur = (const float4*)(u + (size_t)d * Rv);
        const float4* vr = (const float4*)(v + (size_t)d * Rv);
#pragma unroll
        for (int c = 0; c < 4; c++) {
            float4 uu = ur[c], vv = vr[c];
            accq[c * 4 + 0] += hvv[j] * uu.x;
            accq[c * 4 + 1] += hvv[j] * uu.y;
            accq[c * 4 + 2] += hvv[j] * uu.z;
            accq[c * 4 + 3] += hvv[j] * uu.w;
            acck[c * 4 + 0] += hvv[j] * vv.x;
            acck[c * 4 + 1] += hvv[j] * vv.y;
            acck[c * 4 + 2] += hvv[j] * vv.z;
            acck[c * 4 + 3] += hvv[j] * vv.w;
        }
    }
#pragma unroll
    for (int r = 0; r < Rv; r++) {
        for (int off = 32; off > 0; off >>= 1) {
            accq[r] += __shfl_down(accq[r], off);
            acck[r] += __shfl_down(acck[r], off);
        }
    }
    __shared__ float red[4][2 * Rv];
    __shared__ float fin[2 * Rv];
    int lane = t & 63, wid = t >> 6;
    if (lane == 0) {
#pragma unroll
        for (int r = 0; r < Rv; r++) {
            red[wid][r] = accq[r];
            red[wid][Rv + r] = acck[r];
        }
    }
    __syncthreads();
    if (t < 2 * Rv) fin[t] = red[0][t] + red[1][t] + red[2][t] + red[3][t];
    __syncthreads();
    if (t < Rv) {
        float ss = 0.f;
#pragma unroll
        for (int r = 0; r < Rv; r++) { float x = fin[r]; ss += x * x; }
        float nrm = fmaxf(sqrtf(ss), 1e-8f);
        qo[(size_t)row * Rv + t] = fin[t] / nrm;
    } else if (t < 2 * Rv) {
        float ss = 0.f;
#pragma unroll
        for (int r = Rv; r < 2 * Rv; r++) { float x = fin[r]; ss += x * x; }
        float nrm = fmaxf(sqrtf(ss), 1e-8f);
        ko[(size_t)row * Rv + (t - Rv)] = fin[t] / nrm;
    }
}

// ---------------- gamma^delta table: gpow[delta*16 + r] ----------------
__global__ void gpow_kernel(const float* __restrict__ decay_logit,
                            float* __restrict__ gpow) {
    int idx = blockIdx.x * 256 + threadIdx.x;
    if (idx >= Wv * Rv) return;
    int r = idx & (Rv - 1);
    int delta = idx >> 4;
    float gamma = 0.85f + 0.15f * sigmoidf_(decay_logit[r]);
    gpow[idx] = expf((float)delta * logf(gamma));
}

// ---------------- S[b,i,j] = gate*kb[i,j] + alpha*sum_r q*k*gamma^(i-j), causal; bf16 out ----
__global__ void sbuild_kernel(const float* __restrict__ qm, const float* __restrict__ km,
                              const float* __restrict__ kbase,
                              const float* __restrict__ gate_logit,
                              const float* __restrict__ alpha_logit,
                              const float* __restrict__ gpow,
                              bf16* __restrict__ S) {
    int b = blockIdx.z;
    int i = blockIdx.y * 16 + threadIdx.y;
    int j = blockIdx.x * 16 + threadIdx.x;
    bf16* Sp = S + ((size_t)b * Wv + i) * Wv + j;
    if (j > i) { *Sp = (bf16)0.f; return; }
    float gate = sigmoidf_(gate_logit[0]);
    float alpha = sigmoidf_(alpha_logit[0]);
    const float4* qr = (const float4*)(qm + ((size_t)b * Wv + i) * Rv);
    const float4* kr = (const float4*)(km + ((size_t)b * Wv + j) * Rv);
    const float4* gp = (const float4*)(gpow + (size_t)(i - j) * Rv);
    float s = 0.f;
#pragma unroll
    for (int c = 0; c < 4; c++) {
        float4 qq = qr[c], kk = kr[c], gg = gp[c];
        s += qq.x * kk.x * gg.x + qq.y * kk.y * gg.y + qq.z * kk.z * gg.z + qq.w * kk.w * gg.w;
    }
    *Sp = (bf16)(gate * kbase[(size_t)i * Wv + j] + alpha * s);
}

// ---------------- transpose-cast f32 [rows][cols] -> bf16 [cols][rows] ----------------
__global__ void tcast_kernel(const float* __restrict__ in, bf16* __restrict__ out,
                             int rows, int cols, long sIn, long sOut) {
    __shared__ float tile[32][33];
    int bz = blockIdx.z;
    in += (size_t)bz * sIn;
    out += (size_t)bz * sOut;
    int r0 = blockIdx.y * 32, c0 = blockIdx.x * 32;
    int t = threadIdx.x;  // 256
    int r = t >> 3, c4 = (t & 7) * 4;
    float4 v = *(const float4*)(in + (size_t)(r0 + r) * cols + c0 + c4);
    tile[r][c4 + 0] = v.x;
    tile[r][c4 + 1] = v.y;
    tile[r][c4 + 2] = v.z;
    tile[r][c4 + 3] = v.w;
    __syncthreads();
    int n = t >> 3, k4 = (t & 7) * 4;
    bf16x4 ob = {(bf16)tile[k4 + 0][n], (bf16)tile[k4 + 1][n],
                 (bf16)tile[k4 + 2][n], (bf16)tile[k4 + 3][n]};
    *(bf16x4*)(out + (size_t)(c0 + n) * rows + r0 + k4) = ob;
}

// ---------------- MFMA GEMM: C = [gelu](A @ Bt^T + bias) [+ res], A:[M][K] Bt:[N][K] bf16 ----
// BM=BN=BK=64, 256 threads = 4 waves in 2x2; wave computes 32x32.
// LDS tiles XOR-swizzled at 16B granularity: physical granule p in row r holds
// logical granule p^(r&7)  (applied on the global SOURCE address; read side XORs back).
template <bool GELU, bool OUT_BF16, bool HAS_RES, bool CAUSAL>
__global__ __launch_bounds__(256, 4) void mfma_gemm(
    const bf16* __restrict__ A, const bf16* __restrict__ Bt,
    const float* __restrict__ bias, const float* __restrict__ res,
    void* __restrict__ Cout, int M, int N, int K,
    long sA, long sB, long sC) {
    constexpr int BM = 64, BN = 64, BK = 64;
    __shared__ bf16 As[BM * BK];
    __shared__ bf16 Bs[BN * BK];
    int bz = blockIdx.z;
    A += (size_t)bz * sA;
    Bt += (size_t)bz * sB;
    const int m0 = blockIdx.y * BM, n0 = blockIdx.x * BN;
    const int t = threadIdx.x;
    const int lane = t & 63, wid = t >> 6;
    const int wm = wid >> 1, wn = wid & 1;
    f32x4 acc[2][2] = {};

    const int Klim = CAUSAL ? (m0 + BM < K ? m0 + BM : K) : K;

    // staging source (per-lane, swizzled granule)
    const int fr0 = t >> 3;          // row within tile for it=0 (0..31), +32 for it=1
    const int fc = t & 7;            // logical granule this thread would load
    const int fcs = fc ^ (fr0 & 7);  // swizzled granule (row's low 3 bits same for it=0/1)

    // fragment read offsets (element units), swizzle XOR = lane&7 for every fragment row
    const int q = lane >> 4, s = lane & 7, l15 = lane & 15;
    int offA[2][2], offB[2][2];
#pragma unroll
    for (int mi = 0; mi < 2; ++mi)
#pragma unroll
        for (int kk = 0; kk < 2; ++kk) {
            offA[mi][kk] = (wm * 32 + mi * 16 + l15) * BK + (((kk * 4 + q) ^ s) * 8);
            offB[mi][kk] = (wn * 32 + mi * 16 + l15) * BK + (((kk * 4 + q) ^ s) * 8);
        }

    for (int k0 = 0; k0 < Klim; k0 += BK) {
        __syncthreads();  // all waves done reading LDS from previous step
#pragma unroll
        for (int it = 0; it < 2; ++it) {  // A tile: 64x64 bf16 = 8KB
            int r = fr0 + it * 32;
            gload_lds16(A + (size_t)(m0 + r) * K + k0 + fcs * 8,
                        As + it * 2048 + wid * 512);
        }
#pragma unroll
        for (int it = 0; it < 2; ++it) {  // B tile: 64x64 bf16 = 8KB
            int r = fr0 + it * 32;
            gload_lds16(Bt + (size_t)(n0 + r) * K + k0 + fcs * 8,
                        Bs + it * 2048 + wid * 512);
        }
        __syncthreads();  // compiler drains vmcnt before s_barrier

        bf16x8 af[2][2], bfr[2][2];
#pragma unroll
        for (int mi = 0; mi < 2; ++mi)
#pragma unroll
            for (int kk = 0; kk < 2; ++kk) {
                af[mi][kk] = *(const bf16x8*)&As[offA[mi][kk]];
                bfr[mi][kk] = *(const bf16x8*)&Bs[offB[mi][kk]];
            }
#pragma unroll
        for (int kk = 0; kk < 2; ++kk)
#pragma unroll
            for (int mi = 0; mi < 2; ++mi)
#pragma unroll
                for (int ni = 0; ni < 2; ++ni)
                    acc[mi][ni] = __builtin_amdgcn_mfma_f32_16x16x32_bf16(
                        af[mi][kk], bfr[ni][kk], acc[mi][ni], 0, 0, 0);
    }

    const int row_base = m0 + wm * 32;
    const int col_base = n0 + wn * 32;
    const float* resp = HAS_RES ? res + (size_t)bz * sC : nullptr;
#pragma unroll
    for (int mi = 0; mi < 2; ++mi) {
#pragma unroll
        for (int ni = 0; ni < 2; ++ni) {
            int col = col_base + ni * 16 + l15;
            float bv = bias ? bias[col] : 0.f;
#pragma unroll
            for (int r = 0; r < 4; ++r) {
                int row = row_base + mi * 16 + q * 4 + r;
                float val = acc[mi][ni][r] + bv;
                if (GELU) val = 0.5f * val * (1.0f + erff(val * 0.7071067811865476f));
                if (HAS_RES) val += resp[(size_t)row * N + col];
                if (OUT_BF16)
                    ((bf16*)Cout)[(size_t)bz * sC + (size_t)row * N + col] = (bf16)val;
                else
                    ((float*)Cout)[(size_t)bz * sC + (size_t)row * N + col] = val;
            }
        }
    }
}

extern "C" void kernel_launch(void* const* d_in, const int* in_sizes, int n_in,
                              void* d_out, int out_size, void* d_ws, size_t ws_size,
                              hipStream_t stream) {
    const float* h = (const float*)d_in[0];
    const float* decay_logit = (const float*)d_in[1];
    const float* k_base = (const float*)d_in[2];
    const float* gate_logit = (const float*)d_in[3];
    const float* u = (const float*)d_in[4];
    const float* v = (const float*)d_in[5];
    const float* alpha_logit = (const float*)d_in[6];
    const float* proj_w = (const float*)d_in[7];
    const float* proj_b = (const float*)d_in[8];
    const float* n1 = (const float*)d_in[9];
    const float* n2 = (const float*)d_in[10];
    const float* up_w = (const float*)d_in[11];
    const float* up_b = (const float*)d_in[12];
    const float* down_w = (const float*)d_in[13];
    const float* down_b = (const float*)d_in[14];
    float* out = (float*)d_out;

    char* ws = (char*)d_ws;
    float* h_norm = (float*)ws;   ws += (size_t)Bv * Wv * Dv * 4;       // 8 MB f32
    bf16* h_normT = (bf16*)ws;    ws += (size_t)Bv * Dv * Wv * 2;       // 4 MB bf16 [b][D][W]
    float* qm = (float*)ws;       ws += (size_t)Bv * Wv * Rv * 4;
    float* km = (float*)ws;       ws += (size_t)Bv * Wv * Rv * 4;
    float* gpow = (float*)ws;     ws += (size_t)Wv * Rv * 4;
    bf16* S = (bf16*)ws;          ws += (size_t)Bv * Wv * Wv * 2;       // 4 MB
    bf16* out_s = (bf16*)ws;      ws += (size_t)Bv * Wv * Dv * 2;       // 4 MB
    float* h2 = (float*)ws;       ws += (size_t)Bv * Wv * Dv * 4;       // 8 MB
    bf16* h2n = (bf16*)ws;        ws += (size_t)Bv * Wv * Dv * 2;       // 4 MB
    bf16* g = (bf16*)ws;          ws += (size_t)Bv * Wv * 2 * Dv * 2;   // 8 MB
    bf16* proj_wT = (bf16*)ws;    ws += (size_t)Dv * Dv * 2;            // 2 MB
    bf16* up_wT = (bf16*)ws;      ws += (size_t)2 * Dv * Dv * 2;        // 4 MB
    bf16* down_wT = (bf16*)ws;    ws += (size_t)2 * Dv * Dv * 2;        // 4 MB

    int rows = Bv * Wv;  // 2048

    // 1. h_norm = rmsnorm(h, norm1_scale)  (f32, feeds qk + transpose)
    rmsnorm_kernel<false><<<rows, 256, 0, stream>>>(h, n1, h_norm);
    // 2. weight transposes (bf16 [N][K]) + h_norm^T per batch
    tcast_kernel<<<dim3(32, 32, 1), 256, 0, stream>>>(proj_w, proj_wT, Dv, Dv, 0, 0);
    tcast_kernel<<<dim3(64, 32, 1), 256, 0, stream>>>(up_w, up_wT, Dv, 2 * Dv, 0, 0);
    tcast_kernel<<<dim3(32, 64, 1), 256, 0, stream>>>(down_w, down_wT, 2 * Dv, Dv, 0, 0);
    tcast_kernel<<<dim3(32, 32, Bv), 256, 0, stream>>>(h_norm, h_normT, Wv, Dv,
                                                       (long)Wv * Dv, (long)Dv * Wv);
    // 3. q,k
    qk_kernel<<<rows, 256, 0, stream>>>(h_norm, u, v, qm, km);
    // 4. gamma^delta table
    gpow_kernel<<<(Wv * Rv + 255) / 256, 256, 0, stream>>>(decay_logit, gpow);
    // 5. S matrix (bf16)
    sbuild_kernel<<<dim3(Wv / 16, Wv / 16, Bv), dim3(16, 16), 0, stream>>>(
        qm, km, k_base, gate_logit, alpha_logit, gpow, S);
    // 6. out_s = S @ h_norm  (batched, causal-K, bf16 out)
    mfma_gemm<false, true, false, true><<<dim3(Dv / 64, Wv / 64, Bv), 256, 0, stream>>>(
        S, h_normT, nullptr, nullptr, out_s, Wv, Dv, Wv,
        (long)Wv * Wv, (long)Dv * Wv, (long)Wv * Dv);
    // 7. h2 = h + out_s @ proj_w + proj_b  (f32 out)
    mfma_gemm<false, false, true, false><<<dim3(Dv / 64, rows / 64, 1), 256, 0, stream>>>(
        out_s, proj_wT, proj_b, h, h2, rows, Dv, Dv, 0, 0, 0);
    // 8. h2n = rmsnorm(h2, norm2_scale)  (bf16 out)
    rmsnorm_kernel<true><<<rows, 256, 0, stream>>>(h2, n2, h2n);
    // 9. g = gelu(h2n @ up_w + up_b)  (bf16 out)
    mfma_gemm<true, true, false, false><<<dim3(2 * Dv / 64, rows / 64, 1), 256, 0, stream>>>(
        h2n, up_wT, up_b, nullptr, g, rows, 2 * Dv, Dv, 0, 0, 0);
    // 10. out = h2 + g @ down_w + down_b  (f32 out)
    mfma_gemm<false, false, true, false><<<dim3(Dv / 64, rows / 64, 1), 256, 0, stream>>>(
        g, down_wT, down_b, h2, out, rows, Dv, 2 * Dv, 0, 0, 0);
}

// Round 4
// 113.318 us; speedup vs baseline: 4.1382x; 1.3748x over previous
//
#include <hip/hip_runtime.h>

#define Bv 2
#define Wv 1024
#define Dv 1024
#define Rv 16

typedef __bf16 bf16;
typedef __attribute__((ext_vector_type(8))) __bf16 bf16x8;
typedef __attribute__((ext_vector_type(4))) __bf16 bf16x4;
typedef __attribute__((ext_vector_type(4))) float f32x4;

static __device__ __forceinline__ float sigmoidf_(float x) {
    return 1.0f / (1.0f + expf(-x));
}

static __device__ __forceinline__ void gload_lds16(const void* g, void* l) {
    __builtin_amdgcn_global_load_lds(
        (const __attribute__((address_space(1))) unsigned int*)g,
        (__attribute__((address_space(3))) unsigned int*)l, 16, 0, 0);
}

// ---------------- RMSNorm: one block per row, 256 threads, D=1024 ----------------
// MODE 0: write f32 + bf16 row-major.  MODE 1: write bf16 only.
template <int MODE>
__global__ void rmsnorm_kernel(const float* __restrict__ x,
                               const float* __restrict__ scale,
                               float* __restrict__ outf,
                               bf16* __restrict__ outb) {
    int row = blockIdx.x;
    int t = threadIdx.x;
    const float* xr = x + (size_t)row * Dv;
    float4 v = *(const float4*)(xr + t * 4);
    float ss = v.x * v.x + v.y * v.y + v.z * v.z + v.w * v.w;
    for (int off = 32; off > 0; off >>= 1) ss += __shfl_down(ss, off);
    __shared__ float wsum[4];
    __shared__ float inv_s;
    int lane = t & 63, wid = t >> 6;
    if (lane == 0) wsum[wid] = ss;
    __syncthreads();
    if (t == 0) {
        float tot = wsum[0] + wsum[1] + wsum[2] + wsum[3];
        inv_s = rsqrtf(tot * (1.0f / Dv) + 1e-8f);
    }
    __syncthreads();
    float inv = inv_s;
    float4 sc = *(const float4*)(scale + t * 4);
    float o0 = v.x * inv * sc.x;
    float o1 = v.y * inv * sc.y;
    float o2 = v.z * inv * sc.z;
    float o3 = v.w * inv * sc.w;
    if (MODE == 0) {
        float4 o = {o0, o1, o2, o3};
        *(float4*)(outf + (size_t)row * Dv + t * 4) = o;
    }
    bf16x4 ob = {(bf16)o0, (bf16)o1, (bf16)o2, (bf16)o3};
    *(bf16x4*)(outb + (size_t)row * Dv + t * 4) = ob;
}

// ---------------- uvT[32][1024] bf16 from u,v [1024][16] f32 ----------------
__global__ void uvprep_kernel(const float* __restrict__ u, const float* __restrict__ v,
                              bf16* __restrict__ uvT) {
    int idx = blockIdx.x * 256 + threadIdx.x;
    if (idx >= 32 * Wv) return;
    int rcol = idx >> 10;  // 0..31
    int d = idx & (Wv - 1);
    float val = (rcol < Rv) ? u[(size_t)d * Rv + rcol] : v[(size_t)d * Rv + (rcol - Rv)];
    uvT[idx] = (bf16)val;
}

// ---------------- qk via MFMA: [Q|K] = l2norm(hnb @ uvT^T) with gamma folding ----------------
// grid = rows/32 blocks, 256 threads = 4 waves (wm: row half, wn: q-or-k).
// Writes Qs[i][r] = q*gamma_r^i, Ks[j][r] = k*gamma_r^(-j)  (i,j = position within W).
__global__ __launch_bounds__(256) void qk_mfma(
    const bf16* __restrict__ hnb,   // [B*W][D]
    const bf16* __restrict__ uvT,   // [32][D]
    const float* __restrict__ decay_logit,
    bf16* __restrict__ Qs, bf16* __restrict__ Ks) {  // [B*W][16]
    int t = threadIdx.x, lane = t & 63, wid = t >> 6;
    int wm = wid >> 1, wn = wid & 1;
    int row0 = blockIdx.x * 32 + wm * 16;
    const bf16* Arow = hnb + (size_t)(row0 + (lane & 15)) * Dv + (lane >> 4) * 8;
    const bf16* Brow = uvT + (size_t)(wn * 16 + (lane & 15)) * Dv + (lane >> 4) * 8;
    f32x4 acc = {};
#pragma unroll 8
    for (int k0 = 0; k0 < Dv; k0 += 32) {
        bf16x8 a = *(const bf16x8*)(Arow + k0);
        bf16x8 b = *(const bf16x8*)(Brow + k0);
        acc = __builtin_amdgcn_mfma_f32_16x16x32_bf16(a, b, acc, 0, 0, 0);
    }
    int col = lane & 15;  // r index
    float dl = decay_logit[col];
    float gamma = 0.85f + 0.15f * sigmoidf_(dl);
    float logg = log2f(gamma);
#pragma unroll
    for (int r = 0; r < 4; ++r) {
        float vv = acc[r];
        float ss = vv * vv;
#pragma unroll
        for (int m = 1; m < 16; m <<= 1) ss += __shfl_xor(ss, m);
        float nrm = fmaxf(sqrtf(ss), 1e-8f);
        float val = vv / nrm;
        int grow = row0 + (lane >> 4) * 4 + r;  // 0..B*W-1
        int i = grow & (Wv - 1);                // position within W
        if (wn == 0) {
            float pw = exp2f((float)i * logg);
            Qs[(size_t)grow * Rv + col] = (bf16)(val * pw);
        } else {
            float pwi = exp2f(-(float)i * logg);
            Ks[(size_t)grow * Rv + col] = (bf16)(val * pwi);
        }
    }
}

// ---------------- S tile build via MFMA: S = gate*kb + alpha*(Q~ @ K~^T), causal ----------------
// grid (16,16,B); lower-triangular tiles only. 64x64 tile, 4 waves 2x2, K=32 (16 real).
__global__ __launch_bounds__(256) void sbuild_mfma(
    const bf16* __restrict__ Qs, const bf16* __restrict__ Ks,  // [B*W][16]
    const float* __restrict__ kbase,                           // [W][W]
    const float* __restrict__ gate_logit,
    const float* __restrict__ alpha_logit,
    bf16* __restrict__ S) {                                    // [B][W][W]
    int it = blockIdx.y, jt = blockIdx.x;
    if (jt > it) return;
    int b = blockIdx.z;
    int t = threadIdx.x, lane = t & 63, wid = t >> 6;
    int wm = wid >> 1, wn = wid & 1;
    int i0 = it * 64, j0 = jt * 64;
    int l15 = lane & 15, chunk = lane >> 4;
    bf16x8 af[2], bfr[2];
    bf16x8 z8 = {};
#pragma unroll
    for (int mi = 0; mi < 2; ++mi)
        af[mi] = (chunk < 2)
            ? *(const bf16x8*)(Qs + (size_t)(b * Wv + i0 + wm * 32 + mi * 16 + l15) * Rv + chunk * 8)
            : z8;
#pragma unroll
    for (int ni = 0; ni < 2; ++ni)
        bfr[ni] = (chunk < 2)
            ? *(const bf16x8*)(Ks + (size_t)(b * Wv + j0 + wn * 32 + ni * 16 + l15) * Rv + chunk * 8)
            : z8;
    f32x4 acc[2][2] = {};
#pragma unroll
    for (int mi = 0; mi < 2; ++mi)
#pragma unroll
        for (int ni = 0; ni < 2; ++ni)
            acc[mi][ni] = __builtin_amdgcn_mfma_f32_16x16x32_bf16(af[mi], bfr[ni], acc[mi][ni], 0, 0, 0);
    float gate = sigmoidf_(gate_logit[0]);
    float alpha = sigmoidf_(alpha_logit[0]);
#pragma unroll
    for (int mi = 0; mi < 2; ++mi)
#pragma unroll
        for (int ni = 0; ni < 2; ++ni) {
            int j = j0 + wn * 32 + ni * 16 + l15;
#pragma unroll
            for (int r = 0; r < 4; ++r) {
                int i = i0 + wm * 32 + mi * 16 + chunk * 4 + r;
                float s = (j <= i) ? gate * kbase[(size_t)i * Wv + j] + alpha * acc[mi][ni][r] : 0.f;
                S[((size_t)b * Wv + i) * Wv + j] = (bf16)s;
            }
        }
}

// ---------------- transpose-cast f32 [rows][cols] -> bf16 [cols][rows] ----------------
__global__ void tcast_kernel(const float* __restrict__ in, bf16* __restrict__ out,
                             int rows, int cols, long sIn, long sOut) {
    __shared__ float tile[32][33];
    int bz = blockIdx.z;
    in += (size_t)bz * sIn;
    out += (size_t)bz * sOut;
    int r0 = blockIdx.y * 32, c0 = blockIdx.x * 32;
    int t = threadIdx.x;  // 256
    int r = t >> 3, c4 = (t & 7) * 4;
    float4 v = *(const float4*)(in + (size_t)(r0 + r) * cols + c0 + c4);
    tile[r][c4 + 0] = v.x;
    tile[r][c4 + 1] = v.y;
    tile[r][c4 + 2] = v.z;
    tile[r][c4 + 3] = v.w;
    __syncthreads();
    int n = t >> 3, k4 = (t & 7) * 4;
    bf16x4 ob = {(bf16)tile[k4 + 0][n], (bf16)tile[k4 + 1][n],
                 (bf16)tile[k4 + 2][n], (bf16)tile[k4 + 3][n]};
    *(bf16x4*)(out + (size_t)(c0 + n) * rows + r0 + k4) = ob;
}

// ---------------- MFMA GEMM: C = [gelu](A @ Bt^T + bias) [+ res], A:[M][K] Bt:[N][K] bf16 ----
// BM=BN=BK=64, 256 threads = 4 waves in 2x2; wave computes 32x32. XOR-swizzled LDS.
template <bool GELU, bool OUT_BF16, bool HAS_RES, bool CAUSAL>
__global__ __launch_bounds__(256, 4) void mfma_gemm(
    const bf16* __restrict__ A, const bf16* __restrict__ Bt,
    const float* __restrict__ bias, const float* __restrict__ res,
    void* __restrict__ Cout, int M, int N, int K,
    long sA, long sB, long sC) {
    constexpr int BM = 64, BN = 64, BK = 64;
    __shared__ bf16 As[BM * BK];
    __shared__ bf16 Bs[BN * BK];
    int bz = blockIdx.z;
    A += (size_t)bz * sA;
    Bt += (size_t)bz * sB;
    const int m0 = blockIdx.y * BM, n0 = blockIdx.x * BN;
    const int t = threadIdx.x;
    const int lane = t & 63, wid = t >> 6;
    const int wm = wid >> 1, wn = wid & 1;
    f32x4 acc[2][2] = {};

    const int Klim = CAUSAL ? (m0 + BM < K ? m0 + BM : K) : K;

    const int fr0 = t >> 3;
    const int fc = t & 7;
    const int fcs = fc ^ (fr0 & 7);

    const int q = lane >> 4, s = lane & 7, l15 = lane & 15;
    int offA[2][2], offB[2][2];
#pragma unroll
    for (int mi = 0; mi < 2; ++mi)
#pragma unroll
        for (int kk = 0; kk < 2; ++kk) {
            offA[mi][kk] = (wm * 32 + mi * 16 + l15) * BK + (((kk * 4 + q) ^ s) * 8);
            offB[mi][kk] = (wn * 32 + mi * 16 + l15) * BK + (((kk * 4 + q) ^ s) * 8);
        }

    for (int k0 = 0; k0 < Klim; k0 += BK) {
        __syncthreads();
#pragma unroll
        for (int it = 0; it < 2; ++it) {
            int r = fr0 + it * 32;
            gload_lds16(A + (size_t)(m0 + r) * K + k0 + fcs * 8,
                        As + it * 2048 + wid * 512);
        }
#pragma unroll
        for (int it = 0; it < 2; ++it) {
            int r = fr0 + it * 32;
            gload_lds16(Bt + (size_t)(n0 + r) * K + k0 + fcs * 8,
                        Bs + it * 2048 + wid * 512);
        }
        __syncthreads();

        bf16x8 af[2][2], bfr[2][2];
#pragma unroll
        for (int mi = 0; mi < 2; ++mi)
#pragma unroll
            for (int kk = 0; kk < 2; ++kk) {
                af[mi][kk] = *(const bf16x8*)&As[offA[mi][kk]];
                bfr[mi][kk] = *(const bf16x8*)&Bs[offB[mi][kk]];
            }
#pragma unroll
        for (int kk = 0; kk < 2; ++kk)
#pragma unroll
            for (int mi = 0; mi < 2; ++mi)
#pragma unroll
                for (int ni = 0; ni < 2; ++ni)
                    acc[mi][ni] = __builtin_amdgcn_mfma_f32_16x16x32_bf16(
                        af[mi][kk], bfr[ni][kk], acc[mi][ni], 0, 0, 0);
    }

    const int row_base = m0 + wm * 32;
    const int col_base = n0 + wn * 32;
    const float* resp = HAS_RES ? res + (size_t)bz * sC : nullptr;
#pragma unroll
    for (int mi = 0; mi < 2; ++mi) {
#pragma unroll
        for (int ni = 0; ni < 2; ++ni) {
            int col = col_base + ni * 16 + l15;
            float bv = bias ? bias[col] : 0.f;
#pragma unroll
            for (int r = 0; r < 4; ++r) {
                int row = row_base + mi * 16 + q * 4 + r;
                float val = acc[mi][ni][r] + bv;
                if (GELU) val = 0.5f * val * (1.0f + erff(val * 0.7071067811865476f));
                if (HAS_RES) val += resp[(size_t)row * N + col];
                if (OUT_BF16)
                    ((bf16*)Cout)[(size_t)bz * sC + (size_t)row * N + col] = (bf16)val;
                else
                    ((float*)Cout)[(size_t)bz * sC + (size_t)row * N + col] = val;
            }
        }
    }
}

extern "C" void kernel_launch(void* const* d_in, const int* in_sizes, int n_in,
                              void* d_out, int out_size, void* d_ws, size_t ws_size,
                              hipStream_t stream) {
    const float* h = (const float*)d_in[0];
    const float* decay_logit = (const float*)d_in[1];
    const float* k_base = (const float*)d_in[2];
    const float* gate_logit = (const float*)d_in[3];
    const float* u = (const float*)d_in[4];
    const float* v = (const float*)d_in[5];
    const float* alpha_logit = (const float*)d_in[6];
    const float* proj_w = (const float*)d_in[7];
    const float* proj_b = (const float*)d_in[8];
    const float* n1 = (const float*)d_in[9];
    const float* n2 = (const float*)d_in[10];
    const float* up_w = (const float*)d_in[11];
    const float* up_b = (const float*)d_in[12];
    const float* down_w = (const float*)d_in[13];
    const float* down_b = (const float*)d_in[14];
    float* out = (float*)d_out;

    char* ws = (char*)d_ws;
    float* h_norm = (float*)ws;   ws += (size_t)Bv * Wv * Dv * 4;       // 8 MB f32
    bf16* hnb = (bf16*)ws;        ws += (size_t)Bv * Wv * Dv * 2;       // 4 MB bf16 row-major
    bf16* h_normT = (bf16*)ws;    ws += (size_t)Bv * Dv * Wv * 2;       // 4 MB bf16 [b][D][W]
    bf16* uvT = (bf16*)ws;        ws += (size_t)32 * Wv * 2;            // 64 KB
    bf16* Qs = (bf16*)ws;         ws += (size_t)Bv * Wv * Rv * 2;       // 64 KB
    bf16* Ks = (bf16*)ws;         ws += (size_t)Bv * Wv * Rv * 2;       // 64 KB
    bf16* S = (bf16*)ws;          ws += (size_t)Bv * Wv * Wv * 2;       // 4 MB
    bf16* out_s = (bf16*)ws;      ws += (size_t)Bv * Wv * Dv * 2;       // 4 MB
    float* h2 = (float*)ws;       ws += (size_t)Bv * Wv * Dv * 4;       // 8 MB
    bf16* h2n = (bf16*)ws;        ws += (size_t)Bv * Wv * Dv * 2;       // 4 MB
    bf16* g = (bf16*)ws;          ws += (size_t)Bv * Wv * 2 * Dv * 2;   // 8 MB
    bf16* proj_wT = (bf16*)ws;    ws += (size_t)Dv * Dv * 2;            // 2 MB
    bf16* up_wT = (bf16*)ws;      ws += (size_t)2 * Dv * Dv * 2;        // 4 MB
    bf16* down_wT = (bf16*)ws;    ws += (size_t)2 * Dv * Dv * 2;        // 4 MB

    int rows = Bv * Wv;  // 2048

    // 1. h_norm = rmsnorm(h, norm1_scale): f32 + bf16
    rmsnorm_kernel<0><<<rows, 256, 0, stream>>>(h, n1, h_norm, hnb);
    // 2. uvT + weight transposes + h_norm^T
    uvprep_kernel<<<(32 * Wv + 255) / 256, 256, 0, stream>>>(u, v, uvT);
    tcast_kernel<<<dim3(32, 32, 1), 256, 0, stream>>>(proj_w, proj_wT, Dv, Dv, 0, 0);
    tcast_kernel<<<dim3(64, 32, 1), 256, 0, stream>>>(up_w, up_wT, Dv, 2 * Dv, 0, 0);
    tcast_kernel<<<dim3(32, 64, 1), 256, 0, stream>>>(down_w, down_wT, 2 * Dv, Dv, 0, 0);
    tcast_kernel<<<dim3(32, 32, Bv), 256, 0, stream>>>(h_norm, h_normT, Wv, Dv,
                                                       (long)Wv * Dv, (long)Dv * Wv);
    // 3. q,k via MFMA with gamma folding
    qk_mfma<<<rows / 32, 256, 0, stream>>>(hnb, uvT, decay_logit, Qs, Ks);
    // 4. S = gate*kb + alpha*(Q~ @ K~^T), causal tiles only
    sbuild_mfma<<<dim3(Wv / 64, Wv / 64, Bv), 256, 0, stream>>>(
        Qs, Ks, k_base, gate_logit, alpha_logit, S);
    // 5. out_s = S @ h_norm  (batched, causal-K, bf16 out)
    mfma_gemm<false, true, false, true><<<dim3(Dv / 64, Wv / 64, Bv), 256, 0, stream>>>(
        S, h_normT, nullptr, nullptr, out_s, Wv, Dv, Wv,
        (long)Wv * Wv, (long)Dv * Wv, (long)Wv * Dv);
    // 6. h2 = h + out_s @ proj_w + proj_b  (f32 out)
    mfma_gemm<false, false, true, false><<<dim3(Dv / 64, rows / 64, 1), 256, 0, stream>>>(
        out_s, proj_wT, proj_b, h, h2, rows, Dv, Dv, 0, 0, 0);
    // 7. h2n = rmsnorm(h2, norm2_scale)  (bf16 out)
    rmsnorm_kernel<1><<<rows, 256, 0, stream>>>(h2, n2, nullptr, h2n);
    // 8. g = gelu(h2n @ up_w + up_b)  (bf16 out)
    mfma_gemm<true, true, false, false><<<dim3(2 * Dv / 64, rows / 64, 1), 256, 0, stream>>>(
        h2n, up_wT, up_b, nullptr, g, rows, 2 * Dv, Dv, 0, 0, 0);
    // 9. out = h2 + g @ down_w + down_b  (f32 out)
    mfma_gemm<false, false, true, false><<<dim3(Dv / 64, rows / 64, 1), 256, 0, stream>>>(
        g, down_wT, down_b, h2, out, rows, Dv, 2 * Dv, 0, 0, 0);
}

// Round 5
// 98.056 us; speedup vs baseline: 4.7823x; 1.1557x over previous
//
#include <hip/hip_runtime.h>

#define Bv 2
#define Wv 1024
#define Dv 1024
#define Rv 16

typedef __bf16 bf16;
typedef __attribute__((ext_vector_type(8))) __bf16 bf16x8;
typedef __attribute__((ext_vector_type(4))) __bf16 bf16x4;
typedef __attribute__((ext_vector_type(4))) float f32x4;

static __device__ __forceinline__ float sigmoidf_(float x) {
    return 1.0f / (1.0f + expf(-x));
}

static __device__ __forceinline__ void gload_lds16(const void* g, void* l) {
    __builtin_amdgcn_global_load_lds(
        (const __attribute__((address_space(1))) unsigned int*)g,
        (__attribute__((address_space(3))) unsigned int*)l, 16, 0, 0);
}

// ---------------- RMSNorm: one block per row, 256 threads, D=1024, bf16 out ----------------
template <bool INBF16>
__global__ void rmsnorm_kernel(const void* __restrict__ x,
                               const float* __restrict__ scale,
                               bf16* __restrict__ outb) {
    int row = blockIdx.x;
    int t = threadIdx.x;
    float xv[4];
    if (INBF16) {
        bf16x4 v = *(const bf16x4*)((const bf16*)x + (size_t)row * Dv + t * 4);
        xv[0] = (float)v[0]; xv[1] = (float)v[1]; xv[2] = (float)v[2]; xv[3] = (float)v[3];
    } else {
        float4 v = *(const float4*)((const float*)x + (size_t)row * Dv + t * 4);
        xv[0] = v.x; xv[1] = v.y; xv[2] = v.z; xv[3] = v.w;
    }
    float ss = xv[0] * xv[0] + xv[1] * xv[1] + xv[2] * xv[2] + xv[3] * xv[3];
    for (int off = 32; off > 0; off >>= 1) ss += __shfl_down(ss, off);
    __shared__ float wsum[4];
    __shared__ float inv_s;
    int lane = t & 63, wid = t >> 6;
    if (lane == 0) wsum[wid] = ss;
    __syncthreads();
    if (t == 0) {
        float tot = wsum[0] + wsum[1] + wsum[2] + wsum[3];
        inv_s = rsqrtf(tot * (1.0f / Dv) + 1e-8f);
    }
    __syncthreads();
    float inv = inv_s;
    float4 sc = *(const float4*)(scale + t * 4);
    bf16x4 ob = {(bf16)(xv[0] * inv * sc.x), (bf16)(xv[1] * inv * sc.y),
                 (bf16)(xv[2] * inv * sc.z), (bf16)(xv[3] * inv * sc.w)};
    *(bf16x4*)(outb + (size_t)row * Dv + t * 4) = ob;
}

// ---------------- unified prep: weight transposes + h_normT + uvT ----------------
// blocks: [0,1024) proj_wT | [1024,3072) up_wT | [3072,5120) down_wT
//         [5120,7168) h_normT (2 batches) | [7168,7296) uvT
__global__ void prep_kernel(const float* __restrict__ proj_w, const float* __restrict__ up_w,
                            const float* __restrict__ down_w,
                            const float* __restrict__ u, const float* __restrict__ v,
                            const bf16* __restrict__ hnb,
                            bf16* __restrict__ proj_wT, bf16* __restrict__ up_wT,
                            bf16* __restrict__ down_wT, bf16* __restrict__ h_normT,
                            bf16* __restrict__ uvT) {
    __shared__ float tile[32][33];
    int blk = blockIdx.x;
    int t = threadIdx.x;
    if (blk >= 7168) {  // uvT
        int i = (blk - 7168) * 256 + t;
        int rcol = i >> 10, d = i & (Wv - 1);
        float val = (rcol < Rv) ? u[(size_t)d * Rv + rcol] : v[(size_t)d * Rv + (rcol - Rv)];
        uvT[i] = (bf16)val;
        return;
    }
    const void* src;
    bf16* dst;
    int rows, cols, r0, c0;
    bool f32src = true;
    if (blk < 1024) {
        src = proj_w; dst = proj_wT; rows = 1024; cols = 1024;
        c0 = (blk & 31) * 32; r0 = (blk >> 5) * 32;
    } else if (blk < 3072) {
        int idx = blk - 1024;
        src = up_w; dst = up_wT; rows = 1024; cols = 2048;
        c0 = (idx & 63) * 32; r0 = (idx >> 6) * 32;
    } else if (blk < 5120) {
        int idx = blk - 3072;
        src = down_w; dst = down_wT; rows = 2048; cols = 1024;
        c0 = (idx & 31) * 32; r0 = (idx >> 5) * 32;
    } else {
        int idx = blk - 5120;
        int b = idx >> 10; idx &= 1023;
        src = hnb + (size_t)b * Wv * Dv; dst = h_normT + (size_t)b * Dv * Wv;
        rows = 1024; cols = 1024; f32src = false;
        c0 = (idx & 31) * 32; r0 = (idx >> 5) * 32;
    }
    int r = t >> 3, c4 = (t & 7) * 4;
    float vv[4];
    if (f32src) {
        float4 x = *(const float4*)((const float*)src + (size_t)(r0 + r) * cols + c0 + c4);
        vv[0] = x.x; vv[1] = x.y; vv[2] = x.z; vv[3] = x.w;
    } else {
        bf16x4 x = *(const bf16x4*)((const bf16*)src + (size_t)(r0 + r) * cols + c0 + c4);
        vv[0] = (float)x[0]; vv[1] = (float)x[1]; vv[2] = (float)x[2]; vv[3] = (float)x[3];
    }
    tile[r][c4 + 0] = vv[0];
    tile[r][c4 + 1] = vv[1];
    tile[r][c4 + 2] = vv[2];
    tile[r][c4 + 3] = vv[3];
    __syncthreads();
    int n = t >> 3, k4 = (t & 7) * 4;
    bf16x4 ob = {(bf16)tile[k4 + 0][n], (bf16)tile[k4 + 1][n],
                 (bf16)tile[k4 + 2][n], (bf16)tile[k4 + 3][n]};
    *(bf16x4*)(dst + (size_t)(c0 + n) * rows + r0 + k4) = ob;
}

// ---------------- qk via MFMA: [Q|K] = l2norm(hnb @ uvT^T) with gamma folding ----------------
__global__ __launch_bounds__(256) void qk_mfma(
    const bf16* __restrict__ hnb,   // [B*W][D]
    const bf16* __restrict__ uvT,   // [32][D]
    const float* __restrict__ decay_logit,
    bf16* __restrict__ Qs, bf16* __restrict__ Ks) {  // [B*W][16]
    int t = threadIdx.x, lane = t & 63, wid = t >> 6;
    int wm = wid >> 1, wn = wid & 1;
    int row0 = blockIdx.x * 32 + wm * 16;
    const bf16* Arow = hnb + (size_t)(row0 + (lane & 15)) * Dv + (lane >> 4) * 8;
    const bf16* Brow = uvT + (size_t)(wn * 16 + (lane & 15)) * Dv + (lane >> 4) * 8;
    f32x4 acc = {};
#pragma unroll 8
    for (int k0 = 0; k0 < Dv; k0 += 32) {
        bf16x8 a = *(const bf16x8*)(Arow + k0);
        bf16x8 b = *(const bf16x8*)(Brow + k0);
        acc = __builtin_amdgcn_mfma_f32_16x16x32_bf16(a, b, acc, 0, 0, 0);
    }
    int col = lane & 15;  // r index
    float dl = decay_logit[col];
    float gamma = 0.85f + 0.15f * sigmoidf_(dl);
    float logg = log2f(gamma);
#pragma unroll
    for (int r = 0; r < 4; ++r) {
        float vv = acc[r];
        float ss = vv * vv;
#pragma unroll
        for (int m = 1; m < 16; m <<= 1) ss += __shfl_xor(ss, m);
        float nrm = fmaxf(sqrtf(ss), 1e-8f);
        float val = vv / nrm;
        int grow = row0 + (lane >> 4) * 4 + r;
        int i = grow & (Wv - 1);
        if (wn == 0) {
            float pw = exp2f((float)i * logg);
            Qs[(size_t)grow * Rv + col] = (bf16)(val * pw);
        } else {
            float pwi = exp2f(-(float)i * logg);
            Ks[(size_t)grow * Rv + col] = (bf16)(val * pwi);
        }
    }
}

// ---------------- S tile build via MFMA: S = gate*kb + alpha*(Q~ @ K~^T), causal ----------------
__global__ __launch_bounds__(256) void sbuild_mfma(
    const bf16* __restrict__ Qs, const bf16* __restrict__ Ks,
    const float* __restrict__ kbase,
    const float* __restrict__ gate_logit,
    const float* __restrict__ alpha_logit,
    bf16* __restrict__ S) {
    int it = blockIdx.y, jt = blockIdx.x;
    if (jt > it) return;
    int b = blockIdx.z;
    int t = threadIdx.x, lane = t & 63, wid = t >> 6;
    int wm = wid >> 1, wn = wid & 1;
    int i0 = it * 64, j0 = jt * 64;
    int l15 = lane & 15, chunk = lane >> 4;
    bf16x8 af[2], bfr[2];
    bf16x8 z8 = {};
#pragma unroll
    for (int mi = 0; mi < 2; ++mi)
        af[mi] = (chunk < 2)
            ? *(const bf16x8*)(Qs + (size_t)(b * Wv + i0 + wm * 32 + mi * 16 + l15) * Rv + chunk * 8)
            : z8;
#pragma unroll
    for (int ni = 0; ni < 2; ++ni)
        bfr[ni] = (chunk < 2)
            ? *(const bf16x8*)(Ks + (size_t)(b * Wv + j0 + wn * 32 + ni * 16 + l15) * Rv + chunk * 8)
            : z8;
    f32x4 acc[2][2] = {};
#pragma unroll
    for (int mi = 0; mi < 2; ++mi)
#pragma unroll
        for (int ni = 0; ni < 2; ++ni)
            acc[mi][ni] = __builtin_amdgcn_mfma_f32_16x16x32_bf16(af[mi], bfr[ni], acc[mi][ni], 0, 0, 0);
    float gate = sigmoidf_(gate_logit[0]);
    float alpha = sigmoidf_(alpha_logit[0]);
#pragma unroll
    for (int mi = 0; mi < 2; ++mi)
#pragma unroll
        for (int ni = 0; ni < 2; ++ni) {
            int j = j0 + wn * 32 + ni * 16 + l15;
#pragma unroll
            for (int r = 0; r < 4; ++r) {
                int i = i0 + wm * 32 + mi * 16 + chunk * 4 + r;
                float s = (j <= i) ? gate * kbase[(size_t)i * Wv + j] + alpha * acc[mi][ni][r] : 0.f;
                S[((size_t)b * Wv + i) * Wv + j] = (bf16)s;
            }
        }
}

// ---------------- MFMA GEMM: C = [gelu](A @ Bt^T + bias) [+ res], A:[M][K] Bt:[N][K] bf16 ----
// BM=BN=64, BK=128, 256 threads = 4 waves in 2x2; wave computes 32x32. XOR-swizzled LDS.
// RES: 0 none, 1 f32, 2 bf16.
template <bool GELU, bool OUT_BF16, int RES, bool CAUSAL>
__global__ __launch_bounds__(256, 3) void mfma_gemm(
    const bf16* __restrict__ A, const bf16* __restrict__ Bt,
    const float* __restrict__ bias, const void* __restrict__ res,
    void* __restrict__ Cout, int M, int N, int K,
    long sA, long sB, long sC) {
    constexpr int BM = 64, BN = 64, BK = 128;
    __shared__ bf16 As[BM * BK];
    __shared__ bf16 Bs[BN * BK];
    int bz = blockIdx.z;
    A += (size_t)bz * sA;
    Bt += (size_t)bz * sB;
    const int m0 = blockIdx.y * BM, n0 = blockIdx.x * BN;
    const int t = threadIdx.x;
    const int lane = t & 63, wid = t >> 6;
    const int wm = wid >> 1, wn = wid & 1;
    f32x4 acc[2][2] = {};

    const int Klim = CAUSAL ? (m0 + BM < K ? m0 + BM : K) : K;

    // staging: thread t loads 16B granule; row = (t>>4)+16*it, granule fc = t&15,
    // swizzled source granule fcs = fc ^ (row&7); LDS dest linear = it*4KB + t*16B.
    const int srow = t >> 4;
    const int fcs = (t & 15) ^ (srow & 7);

    const int q = lane >> 4, s = lane & 7, l15 = lane & 15;

    for (int k0 = 0; k0 < Klim; k0 += BK) {
        __syncthreads();
#pragma unroll
        for (int it = 0; it < 4; ++it) {
            int r = srow + it * 16;
            gload_lds16(A + (size_t)(m0 + r) * K + k0 + fcs * 8,
                        As + it * 2048 + wid * 512);
        }
#pragma unroll
        for (int it = 0; it < 4; ++it) {
            int r = srow + it * 16;
            gload_lds16(Bt + (size_t)(n0 + r) * K + k0 + fcs * 8,
                        Bs + it * 2048 + wid * 512);
        }
        __syncthreads();

        bf16x8 af[2][4], bfr[2][4];
#pragma unroll
        for (int mi = 0; mi < 2; ++mi)
#pragma unroll
            for (int kk = 0; kk < 4; ++kk) {
                af[mi][kk] = *(const bf16x8*)&As[(wm * 32 + mi * 16 + l15) * BK + (((kk * 4 + q) ^ s) * 8)];
                bfr[mi][kk] = *(const bf16x8*)&Bs[(wn * 32 + mi * 16 + l15) * BK + (((kk * 4 + q) ^ s) * 8)];
            }
#pragma unroll
        for (int kk = 0; kk < 4; ++kk)
#pragma unroll
            for (int mi = 0; mi < 2; ++mi)
#pragma unroll
                for (int ni = 0; ni < 2; ++ni)
                    acc[mi][ni] = __builtin_amdgcn_mfma_f32_16x16x32_bf16(
                        af[mi][kk], bfr[ni][kk], acc[mi][ni], 0, 0, 0);
    }

    const int row_base = m0 + wm * 32;
    const int col_base = n0 + wn * 32;
#pragma unroll
    for (int mi = 0; mi < 2; ++mi) {
#pragma unroll
        for (int ni = 0; ni < 2; ++ni) {
            int col = col_base + ni * 16 + l15;
            float bv = bias ? bias[col] : 0.f;
#pragma unroll
            for (int r = 0; r < 4; ++r) {
                int row = row_base + mi * 16 + q * 4 + r;
                float val = acc[mi][ni][r] + bv;
                if (GELU) val = 0.5f * val * (1.0f + erff(val * 0.7071067811865476f));
                if (RES == 1)
                    val += ((const float*)res)[(size_t)bz * sC + (size_t)row * N + col];
                else if (RES == 2)
                    val += (float)((const bf16*)res)[(size_t)bz * sC + (size_t)row * N + col];
                if (OUT_BF16)
                    ((bf16*)Cout)[(size_t)bz * sC + (size_t)row * N + col] = (bf16)val;
                else
                    ((float*)Cout)[(size_t)bz * sC + (size_t)row * N + col] = val;
            }
        }
    }
}

extern "C" void kernel_launch(void* const* d_in, const int* in_sizes, int n_in,
                              void* d_out, int out_size, void* d_ws, size_t ws_size,
                              hipStream_t stream) {
    const float* h = (const float*)d_in[0];
    const float* decay_logit = (const float*)d_in[1];
    const float* k_base = (const float*)d_in[2];
    const float* gate_logit = (const float*)d_in[3];
    const float* u = (const float*)d_in[4];
    const float* v = (const float*)d_in[5];
    const float* alpha_logit = (const float*)d_in[6];
    const float* proj_w = (const float*)d_in[7];
    const float* proj_b = (const float*)d_in[8];
    const float* n1 = (const float*)d_in[9];
    const float* n2 = (const float*)d_in[10];
    const float* up_w = (const float*)d_in[11];
    const float* up_b = (const float*)d_in[12];
    const float* down_w = (const float*)d_in[13];
    const float* down_b = (const float*)d_in[14];
    float* out = (float*)d_out;

    char* ws = (char*)d_ws;
    bf16* hnb = (bf16*)ws;        ws += (size_t)Bv * Wv * Dv * 2;       // 4 MB
    bf16* h_normT = (bf16*)ws;    ws += (size_t)Bv * Dv * Wv * 2;       // 4 MB
    bf16* uvT = (bf16*)ws;        ws += (size_t)32 * Wv * 2;            // 64 KB
    bf16* Qs = (bf16*)ws;         ws += (size_t)Bv * Wv * Rv * 2;       // 64 KB
    bf16* Ks = (bf16*)ws;         ws += (size_t)Bv * Wv * Rv * 2;       // 64 KB
    bf16* S = (bf16*)ws;          ws += (size_t)Bv * Wv * Wv * 2;       // 4 MB
    bf16* out_s = (bf16*)ws;      ws += (size_t)Bv * Wv * Dv * 2;       // 4 MB
    bf16* h2b = (bf16*)ws;        ws += (size_t)Bv * Wv * Dv * 2;       // 4 MB
    bf16* h2n = (bf16*)ws;        ws += (size_t)Bv * Wv * Dv * 2;       // 4 MB
    bf16* g = (bf16*)ws;          ws += (size_t)Bv * Wv * 2 * Dv * 2;   // 8 MB
    bf16* proj_wT = (bf16*)ws;    ws += (size_t)Dv * Dv * 2;            // 2 MB
    bf16* up_wT = (bf16*)ws;      ws += (size_t)2 * Dv * Dv * 2;        // 4 MB
    bf16* down_wT = (bf16*)ws;    ws += (size_t)2 * Dv * Dv * 2;        // 4 MB

    int rows = Bv * Wv;  // 2048

    // 1. hnb = rmsnorm(h, norm1_scale) bf16
    rmsnorm_kernel<false><<<rows, 256, 0, stream>>>(h, n1, hnb);
    // 2. all transposes + uvT in one launch
    prep_kernel<<<7296, 256, 0, stream>>>(proj_w, up_w, down_w, u, v, hnb,
                                          proj_wT, up_wT, down_wT, h_normT, uvT);
    // 3. q,k via MFMA with gamma folding
    qk_mfma<<<rows / 32, 256, 0, stream>>>(hnb, uvT, decay_logit, Qs, Ks);
    // 4. S = gate*kb + alpha*(Q~ @ K~^T), causal tiles
    sbuild_mfma<<<dim3(Wv / 64, Wv / 64, Bv), 256, 0, stream>>>(
        Qs, Ks, k_base, gate_logit, alpha_logit, S);
    // 5. out_s = S @ h_norm  (batched, causal-K, bf16 out)
    mfma_gemm<false, true, 0, true><<<dim3(Dv / 64, Wv / 64, Bv), 256, 0, stream>>>(
        S, h_normT, nullptr, nullptr, out_s, Wv, Dv, Wv,
        (long)Wv * Wv, (long)Dv * Wv, (long)Wv * Dv);
    // 6. h2b = h + out_s @ proj_w + proj_b  (bf16 out, f32 res)
    mfma_gemm<false, true, 1, false><<<dim3(Dv / 64, rows / 64, 1), 256, 0, stream>>>(
        out_s, proj_wT, proj_b, h, h2b, rows, Dv, Dv, 0, 0, 0);
    // 7. h2n = rmsnorm(h2b, norm2_scale)  (bf16 in/out)
    rmsnorm_kernel<true><<<rows, 256, 0, stream>>>(h2b, n2, h2n);
    // 8. g = gelu(h2n @ up_w + up_b)  (bf16 out)
    mfma_gemm<true, true, 0, false><<<dim3(2 * Dv / 64, rows / 64, 1), 256, 0, stream>>>(
        h2n, up_wT, up_b, nullptr, g, rows, 2 * Dv, Dv, 0, 0, 0);
    // 9. out = h2b + g @ down_w + down_b  (f32 out, bf16 res)
    mfma_gemm<false, false, 2, false><<<dim3(Dv / 64, rows / 64, 1), 256, 0, stream>>>(
        g, down_wT, down_b, h2b, out, rows, Dv, 2 * Dv, 0, 0, 0);
}